// Round 1
// baseline (753.531 us; speedup 1.0000x reference)
//
#include <hip/hip_runtime.h>
#include <hip/hip_bf16.h>

// ---------------------------------------------------------------------------
// SemanticComposite: attention-like mix + 3-gate GRU-ish combine.
//  scores[b,i,j] = a_i + b_j + (x_i*wc). x_j ; a_i drops out of softmax(j).
//  attn = softmax(scores) @ x ; cat=[x,attn];
//  out = sig(cat@r_w^T+rb)*x + sig(cat@f_w^T+fb)*tanh(cat@z_w^T+zb)
// Strategy: bf16 MFMA 16x16x32 everywhere; flash attention with per-wave
// j-parity split; fragment-linear prepacked weights for the gate GEMMs.
// ---------------------------------------------------------------------------

typedef unsigned short u16;
typedef unsigned int   u32;
typedef u16   u16x8 __attribute__((ext_vector_type(8)));
typedef u16   u16x4 __attribute__((ext_vector_type(4)));
typedef short s16x8 __attribute__((ext_vector_type(8)));
typedef float f32x4 __attribute__((ext_vector_type(4)));

#define MFMA16(a,b,c) __builtin_amdgcn_mfma_f32_16x16x32_bf16( \
    __builtin_bit_cast(s16x8,(a)), __builtin_bit_cast(s16x8,(b)), (c), 0, 0, 0)

// XOR swizzle: spreads 16B chunks of stride-64B rows across banks.
#define SWZ(r) ((((r) ^ ((r) >> 3)) & 3))

static __device__ __forceinline__ u16 f2bf(float f) {
  __hip_bfloat16 h = __float2bfloat16(f);
  return *reinterpret_cast<u16*>(&h);
}

#define NB   8
#define NS   2048
#define NF   256
#define NR   (NB*NS)          // 16384 rows

// ---------------- prep: qb = bf16(x*wc), xb = bf16(x), bvec = x.wb ---------
__global__ __launch_bounds__(256) void k_prep(const float* __restrict__ x,
                                              const float* __restrict__ attw,
                                              u16* __restrict__ qb,
                                              u16* __restrict__ xb,
                                              float* __restrict__ bvec) {
  const int lane = threadIdx.x & 63, w = threadIdx.x >> 6;
  const int row = blockIdx.x * 4 + w;                 // 0..16383
  const float4 xv = *reinterpret_cast<const float4*>(x + (size_t)row * NF + lane * 4);
  const float4 wc = *reinterpret_cast<const float4*>(attw + 2 * NF + lane * 4);
  const float4 wb = *reinterpret_cast<const float4*>(attw + NF + lane * 4);
  u16x4 q, xq;
  q[0] = f2bf(xv.x * wc.x); q[1] = f2bf(xv.y * wc.y);
  q[2] = f2bf(xv.z * wc.z); q[3] = f2bf(xv.w * wc.w);
  xq[0] = f2bf(xv.x); xq[1] = f2bf(xv.y); xq[2] = f2bf(xv.z); xq[3] = f2bf(xv.w);
  *reinterpret_cast<u16x4*>(qb + (size_t)row * NF + lane * 4) = q;
  *reinterpret_cast<u16x4*>(xb + (size_t)row * NF + lane * 4) = xq;
  float s = xv.x * wb.x + xv.y * wb.y + xv.z * wb.z + xv.w * wb.w;
  #pragma unroll
  for (int m = 1; m < 64; m <<= 1) s += __shfl_xor(s, m, 64);
  if (lane == 0) bvec[row] = s;
}

// ---------------- weight repack to B-fragment-linear bf16 ------------------
// wfrag[w][ks][nt][lane][i] = W[16*nt + (lane&15)][32*ks + 8*(lane>>4) + i]
__global__ __launch_bounds__(64) void k_wrep(const float* __restrict__ zw,
                                             const float* __restrict__ rw,
                                             const float* __restrict__ fw,
                                             u16* __restrict__ wfrag) {
  const int lane = threadIdx.x & 63;
  const int idx = blockIdx.x;                   // 0..767
  const int w = idx >> 8, rem = idx & 255, ks = rem >> 4, nt = rem & 15;
  const float* W = (w == 0) ? zw : ((w == 1) ? rw : fw);
  const int n = lane & 15, g = lane >> 4;
  const float* src = W + (size_t)(nt * 16 + n) * 512 + ks * 32 + g * 8;
  u16x8 o;
  #pragma unroll
  for (int i = 0; i < 8; ++i) o[i] = f2bf(src[i]);
  *reinterpret_cast<u16x8*>(wfrag + ((size_t)(w * 256 + ks * 16 + nt) * 64 + lane) * 8) = o;
}

// ---------------- flash attention ------------------------------------------
// grid 256 = (b, 64-row i-tile). 4 waves; each wave: all 64 rows, j-tiles
// with jt % 4 == wave. K-fragments direct from global (L2); V transposed
// into per-wave swizzled LDS; P via swizzled LDS roundtrip. 4-way flash
// combine at the end.
__global__ __launch_bounds__(256, 1) void k_attn(const u16* __restrict__ qb,
                                                 const u16* __restrict__ xb,
                                                 const float* __restrict__ bvec,
                                                 u16* __restrict__ attnb) {
  extern __shared__ u16 lds[];
  // [0,65536): Vt[4 parity][256 f][32 j] bf16 (swizzled); reused as CMB f32[4][64][64]
  // [65536,81920): Pl[4 wave][64 row][32 j] bf16 (swizzled)
  // [81920,83968): ML float[4 wave][2][64 row]
  const int tid = threadIdx.x;
  const int w = tid >> 6, lane = tid & 63;
  const int n = lane & 15, g = lane >> 4;
  const int b = blockIdx.x >> 5, itile = blockIdx.x & 31;
  const int i0 = itile * 64;
  const size_t xbase = (size_t)b * (NS * NF);

  u16* vt = lds + w * 8192;                      // this wave's V^T tile
  u16* pl = lds + 4 * 8192 + w * 2048;           // this wave's P tile
  float* ML = reinterpret_cast<float*>(lds + 4 * 8192 + 4 * 2048);

  // Q fragments (held in registers whole kernel): 4 mfrag x 8 ks
  u16x8 qf[4][8];
  #pragma unroll
  for (int mf = 0; mf < 4; ++mf) {
    const u16* qrow = qb + xbase + (size_t)(i0 + 16 * mf + n) * NF + 8 * g;
    #pragma unroll
    for (int ks = 0; ks < 8; ++ks) qf[mf][ks] = *reinterpret_cast<const u16x8*>(qrow + 32 * ks);
  }

  f32x4 O[4][16];
  #pragma unroll
  for (int mf = 0; mf < 4; ++mf)
    #pragma unroll
    for (int nf = 0; nf < 16; ++nf) O[mf][nf] = 0.f;
  float mrow[4][4], lrow[4][4];
  #pragma unroll
  for (int mf = 0; mf < 4; ++mf)
    #pragma unroll
    for (int r = 0; r < 4; ++r) { mrow[mf][r] = -__builtin_inff(); lrow[mf][r] = 0.f; }

  for (int jt = w; jt < 64; jt += 4) {
    const int j0 = jt * 32;
    // ---- stage V^T (pair-packed b32, swizzled), own wave only -------------
    {
      const int p = lane >> 2, a = lane & 3;       // j-pair, f-chunk
      #pragma unroll
      for (int it2 = 0; it2 < 8; ++it2) {
        const int c = 8 * (a + 4 * it2);
        const u16* r0 = xb + xbase + (size_t)(j0 + 2 * p) * NF + c;
        u16x8 v0 = *reinterpret_cast<const u16x8*>(r0);
        u16x8 v1 = *reinterpret_cast<const u16x8*>(r0 + NF);
        #pragma unroll
        for (int i = 0; i < 8; ++i) {
          const int f = c + i;
          const u32 pk = (u32)v0[i] | ((u32)v1[i] << 16);
          const int byte = (f * 64 + 4 * p) ^ (SWZ(f) << 4);
          *reinterpret_cast<u32*>(reinterpret_cast<char*>(vt) + byte) = pk;
        }
      }
    }
    // ---- QK^T: scores (4 mfrag x 2 nf), K B-frags direct from global ------
    f32x4 sc[4][2];
    #pragma unroll
    for (int nf = 0; nf < 2; ++nf) {
      f32x4 acc[4]; 
      #pragma unroll
      for (int mf = 0; mf < 4; ++mf) acc[mf] = 0.f;
      const u16* krow = xb + xbase + (size_t)(j0 + 16 * nf + n) * NF + 8 * g;
      #pragma unroll
      for (int ks = 0; ks < 8; ++ks) {
        u16x8 kf = *reinterpret_cast<const u16x8*>(krow + 32 * ks);
        #pragma unroll
        for (int mf = 0; mf < 4; ++mf) acc[mf] = MFMA16(qf[mf][ks], kf, acc[mf]);
      }
      const float bv = bvec[b * NS + j0 + 16 * nf + n];
      #pragma unroll
      for (int mf = 0; mf < 4; ++mf)
        #pragma unroll
        for (int r = 0; r < 4; ++r) sc[mf][nf][r] = acc[mf][r] + bv;
    }
    // ---- online softmax ---------------------------------------------------
    float pmax[4][4];
    #pragma unroll
    for (int mf = 0; mf < 4; ++mf)
      #pragma unroll
      for (int r = 0; r < 4; ++r) {
        float v = fmaxf(sc[mf][0][r], sc[mf][1][r]);
        #pragma unroll
        for (int m = 1; m < 16; m <<= 1) v = fmaxf(v, __shfl_xor(v, m, 64));
        pmax[mf][r] = v;
      }
    int needi = 0;
    #pragma unroll
    for (int mf = 0; mf < 4; ++mf)
      #pragma unroll
      for (int r = 0; r < 4; ++r) needi |= (pmax[mf][r] > mrow[mf][r] + 8.0f) ? 1 : 0;
    if (__any(needi)) {             // T13 defer-max: rescale only when needed
      float scl[4][4];
      #pragma unroll
      for (int mf = 0; mf < 4; ++mf)
        #pragma unroll
        for (int r = 0; r < 4; ++r) {
          const float mn = fmaxf(mrow[mf][r], pmax[mf][r]);
          scl[mf][r] = __expf(mrow[mf][r] - mn);
          mrow[mf][r] = mn;
          lrow[mf][r] *= scl[mf][r];
        }
      #pragma unroll
      for (int mf = 0; mf < 4; ++mf)
        #pragma unroll
        for (int nf = 0; nf < 16; ++nf)
          #pragma unroll
          for (int r = 0; r < 4; ++r) O[mf][nf][r] *= scl[mf][r];
    }
    float p[4][2][4];
    #pragma unroll
    for (int mf = 0; mf < 4; ++mf)
      #pragma unroll
      for (int nf = 0; nf < 2; ++nf)
        #pragma unroll
        for (int r = 0; r < 4; ++r) p[mf][nf][r] = __expf(sc[mf][nf][r] - mrow[mf][r]);
    #pragma unroll
    for (int mf = 0; mf < 4; ++mf)
      #pragma unroll
      for (int r = 0; r < 4; ++r) {
        float s = p[mf][0][r] + p[mf][1][r];
        #pragma unroll
        for (int m = 1; m < 16; m <<= 1) s += __shfl_xor(s, m, 64);
        lrow[mf][r] += s;
      }
    // ---- P -> LDS (swizzled) -> A-frags -----------------------------------
    #pragma unroll
    for (int mf = 0; mf < 4; ++mf)
      #pragma unroll
      for (int nf = 0; nf < 2; ++nf)
        #pragma unroll
        for (int r = 0; r < 4; ++r) {
          const int row = 16 * mf + 4 * g + r, col = 16 * nf + n;
          const int byte = (row * 64 + 2 * col) ^ (SWZ(row) << 4);
          *reinterpret_cast<u16*>(reinterpret_cast<char*>(pl) + byte) = f2bf(p[mf][nf][r]);
        }
    u16x8 pa[4];
    #pragma unroll
    for (int mf = 0; mf < 4; ++mf) {
      const int row = 16 * mf + n;
      const int byte = (row * 64 + 16 * g) ^ (SWZ(row) << 4);
      pa[mf] = *reinterpret_cast<const u16x8*>(reinterpret_cast<char*>(pl) + byte);
    }
    // ---- PV ---------------------------------------------------------------
    #pragma unroll
    for (int nf16 = 0; nf16 < 16; ++nf16) {
      const int fr = 16 * nf16 + n;
      const int byte = (fr * 64 + 16 * g) ^ (SWZ(fr) << 4);
      u16x8 vf = *reinterpret_cast<const u16x8*>(reinterpret_cast<char*>(vt) + byte);
      #pragma unroll
      for (int mf = 0; mf < 4; ++mf) O[mf][nf16] = MFMA16(pa[mf], vf, O[mf][nf16]);
    }
  }

  // ---- 4-way flash combine across waves -----------------------------------
  __syncthreads();
  {
    float* mlw = ML + w * 128;
    if (n == 0) {
      #pragma unroll
      for (int mf = 0; mf < 4; ++mf)
        #pragma unroll
        for (int r = 0; r < 4; ++r) {
          const int row = 16 * mf + 4 * g + r;
          mlw[row] = mrow[mf][r];
          mlw[64 + row] = lrow[mf][r];
        }
    }
  }
  __syncthreads();
  float Lrow[4][4];
  {
    #pragma unroll
    for (int mf = 0; mf < 4; ++mf)
      #pragma unroll
      for (int r = 0; r < 4; ++r) {
        const int row = 16 * mf + 4 * g + r;
        float M = -__builtin_inff();
        #pragma unroll
        for (int w2 = 0; w2 < 4; ++w2) M = fmaxf(M, ML[w2 * 128 + row]);
        float L = 0.f;
        #pragma unroll
        for (int w2 = 0; w2 < 4; ++w2) L += ML[w2 * 128 + 64 + row] * __expf(ML[w2 * 128 + row] - M);
        const float fac = __expf(mrow[mf][r] - M);
        Lrow[mf][r] = L;
        #pragma unroll
        for (int nf = 0; nf < 16; ++nf) O[mf][nf][r] *= fac;
      }
  }
  __syncthreads();
  float* CMB = reinterpret_cast<float*>(lds);       // 4 slots x [64][64] f32
  for (int s = 1; s < 4; ++s) {
    const int cw = (w + s) & 3;
    float* slot = CMB + cw * 4096;
    #pragma unroll
    for (int nf2 = 0; nf2 < 4; ++nf2) {
      const int nf16 = 4 * cw + nf2;
      #pragma unroll
      for (int mf = 0; mf < 4; ++mf)
        #pragma unroll
        for (int r = 0; r < 4; ++r)
          slot[(16 * mf + 4 * g + r) * 64 + 16 * nf2 + n] = O[mf][nf16][r];
    }
    __syncthreads();
    const float* my = CMB + w * 4096;
    #pragma unroll
    for (int nf2 = 0; nf2 < 4; ++nf2) {
      const int nf16 = 4 * w + nf2;
      #pragma unroll
      for (int mf = 0; mf < 4; ++mf)
        #pragma unroll
        for (int r = 0; r < 4; ++r)
          O[mf][nf16][r] += my[(16 * mf + 4 * g + r) * 64 + 16 * nf2 + n];
    }
    __syncthreads();
  }
  // final write: wave w owns f-cols [64w, 64w+64)
  #pragma unroll
  for (int nf2 = 0; nf2 < 4; ++nf2) {
    const int nf16 = 4 * w + nf2;
    #pragma unroll
    for (int mf = 0; mf < 4; ++mf)
      #pragma unroll
      for (int r = 0; r < 4; ++r) {
        const int row = i0 + 16 * mf + 4 * g + r;
        const float v = O[mf][nf16][r] / Lrow[mf][r];
        attnb[xbase + (size_t)row * NF + 16 * nf16 + n] = f2bf(v);
      }
  }
}

// ---------------- fused gate GEMMs + epilogue ------------------------------
// 256 blocks x 64 rows. wave: (rg = w&1) 32 rows, (nh = w>>1) 128 cols.
// 2 m-frags per wave -> each weight fragment reused 2x.
__global__ __launch_bounds__(256, 1) void k_gate(const u16* __restrict__ xb,
                                                 const u16* __restrict__ attnb,
                                                 const float* __restrict__ x,
                                                 const float* __restrict__ zb,
                                                 const float* __restrict__ rb,
                                                 const float* __restrict__ fb,
                                                 const u16* __restrict__ wfrag,
                                                 float* __restrict__ out) {
  const int tid = threadIdx.x, w = tid >> 6, lane = tid & 63;
  const int rg = w & 1, nh = w >> 1;
  const int m0 = blockIdx.x * 64 + rg * 32;
  const int n = lane & 15, g = lane >> 4;

  u16x8 af[2][16];
  #pragma unroll
  for (int mf = 0; mf < 2; ++mf) {
    const int row = m0 + 16 * mf + n;
    const u16* xr = xb + (size_t)row * NF + 8 * g;
    #pragma unroll
    for (int ks = 0; ks < 8; ++ks) af[mf][ks] = *reinterpret_cast<const u16x8*>(xr + 32 * ks);
    const u16* ar = attnb + (size_t)row * NF + 8 * g;
    #pragma unroll
    for (int ks = 0; ks < 8; ++ks) af[mf][8 + ks] = *reinterpret_cast<const u16x8*>(ar + 32 * ks);
  }
  for (int nt2 = 0; nt2 < 8; ++nt2) {
    const int nt = 8 * nh + nt2;
    const int col = 16 * nt + n;
    f32x4 za[2], ra[2], fa[2];
    {
      const float z0 = zb[col], r0 = rb[col], f0 = fb[col];
      #pragma unroll
      for (int mf = 0; mf < 2; ++mf) { za[mf] = z0; ra[mf] = r0; fa[mf] = f0; }
    }
    #pragma unroll
    for (int ks = 0; ks < 16; ++ks) {
      const size_t base = ((size_t)(ks * 16 + nt) * 64 + lane) * 8;
      u16x8 bz = *reinterpret_cast<const u16x8*>(wfrag + base);
      u16x8 br = *reinterpret_cast<const u16x8*>(wfrag + (size_t)256 * 64 * 8 + base);
      u16x8 bff = *reinterpret_cast<const u16x8*>(wfrag + (size_t)512 * 64 * 8 + base);
      #pragma unroll
      for (int mf = 0; mf < 2; ++mf) {
        za[mf] = MFMA16(af[mf][ks], bz, za[mf]);
        ra[mf] = MFMA16(af[mf][ks], br, ra[mf]);
        fa[mf] = MFMA16(af[mf][ks], bff, fa[mf]);
      }
    }
    #pragma unroll
    for (int mf = 0; mf < 2; ++mf)
      #pragma unroll
      for (int r = 0; r < 4; ++r) {
        const int row = m0 + 16 * mf + 4 * g + r;
        const float xv = x[(size_t)row * NF + col];
        const float zv = 2.f / (1.f + __expf(-2.f * za[mf][r])) - 1.f;  // tanh
        const float rv = 1.f / (1.f + __expf(-ra[mf][r]));
        const float fv = 1.f / (1.f + __expf(-fa[mf][r]));
        out[(size_t)row * NF + col] = rv * xv + fv * zv;
      }
  }
}

// ---------------------------------------------------------------------------
extern "C" void kernel_launch(void* const* d_in, const int* in_sizes, int n_in,
                              void* d_out, int out_size, void* d_ws, size_t ws_size,
                              hipStream_t stream) {
  const float* x    = (const float*)d_in[0];
  const float* attw = (const float*)d_in[1];
  const float* zw   = (const float*)d_in[2];
  const float* zb   = (const float*)d_in[3];
  const float* rw   = (const float*)d_in[4];
  const float* rb   = (const float*)d_in[5];
  const float* fw   = (const float*)d_in[6];
  const float* fb   = (const float*)d_in[7];
  float* out = (float*)d_out;

  char* ws = (char*)d_ws;
  u16*   qb    = (u16*)(ws);                       //  8 MB
  u16*   xbb   = (u16*)(ws + 8388608);             //  8 MB
  u16*   attnb = (u16*)(ws + 16777216);            //  8 MB
  float* bvec  = (float*)(ws + 25165824);          // 64 KB
  u16*   wfrag = (u16*)(ws + 25231360);            // 768 KB  (total ~24.8 MB)

  (void)hipFuncSetAttribute((const void*)k_attn,
      hipFuncAttributeMaxDynamicSharedMemorySize, 83968);

  k_prep<<<NR / 4, 256, 0, stream>>>(x, attw, qb, xbb, bvec);
  k_wrep<<<768, 64, 0, stream>>>(zw, rw, fw, wfrag);
  k_attn<<<256, 256, 83968, stream>>>(qb, xbb, bvec, attnb);
  k_gate<<<256, 256, 0, stream>>>(xbb, attnb, x, zb, rb, fb, wfrag, out);
}

// Round 4
// 352.496 us; speedup vs baseline: 2.1377x; 2.1377x over previous
//
#include <hip/hip_runtime.h>
#include <hip/hip_bf16.h>

// ---------------------------------------------------------------------------
// SemanticComposite: attention-like mix + 3-gate combine.
//  scores[b,i,j] = a_i + b_j + (x_i*wc).x_j ; a_i drops out of softmax(j).
//  attn = softmax(scores) @ x ; cat=[x,attn];
//  out = sig(cat@r_w^T+rb)*x + sig(cat@f_w^T+fb)*tanh(cat@z_w^T+zb)
// R2: attention restructured -- 16 rows/wave (no O spills), 8 waves with
// 2-way j-split + LDS flash-merge, XCD-aware batch swizzle.
// (R4 = R2 resubmitted: rounds 2 and 3 both hit GPU-acquisition timeouts.)
// ---------------------------------------------------------------------------

typedef unsigned short u16;
typedef unsigned int   u32;
typedef u16   u16x8 __attribute__((ext_vector_type(8)));
typedef u16   u16x4 __attribute__((ext_vector_type(4)));
typedef short s16x8 __attribute__((ext_vector_type(8)));
typedef float f32x4 __attribute__((ext_vector_type(4)));

#define MFMA16(a,b,c) __builtin_amdgcn_mfma_f32_16x16x32_bf16( \
    __builtin_bit_cast(s16x8,(a)), __builtin_bit_cast(s16x8,(b)), (c), 0, 0, 0)

static __device__ __forceinline__ u16 f2bf(float f) {
  __hip_bfloat16 h = __float2bfloat16(f);
  return *reinterpret_cast<u16*>(&h);
}

#define NB   8
#define NS   2048
#define NF   256
#define NR   (NB*NS)          // 16384 rows

// ---------------- prep: qb = bf16(x*wc), xb = bf16(x), bvec = x.wb ---------
__global__ __launch_bounds__(256) void k_prep(const float* __restrict__ x,
                                              const float* __restrict__ attw,
                                              u16* __restrict__ qb,
                                              u16* __restrict__ xb,
                                              float* __restrict__ bvec) {
  const int lane = threadIdx.x & 63, w = threadIdx.x >> 6;
  const int row = blockIdx.x * 4 + w;                 // 0..16383
  const float4 xv = *reinterpret_cast<const float4*>(x + (size_t)row * NF + lane * 4);
  const float4 wc = *reinterpret_cast<const float4*>(attw + 2 * NF + lane * 4);
  const float4 wb = *reinterpret_cast<const float4*>(attw + NF + lane * 4);
  u16x4 q, xq;
  q[0] = f2bf(xv.x * wc.x); q[1] = f2bf(xv.y * wc.y);
  q[2] = f2bf(xv.z * wc.z); q[3] = f2bf(xv.w * wc.w);
  xq[0] = f2bf(xv.x); xq[1] = f2bf(xv.y); xq[2] = f2bf(xv.z); xq[3] = f2bf(xv.w);
  *reinterpret_cast<u16x4*>(qb + (size_t)row * NF + lane * 4) = q;
  *reinterpret_cast<u16x4*>(xb + (size_t)row * NF + lane * 4) = xq;
  float s = xv.x * wb.x + xv.y * wb.y + xv.z * wb.z + xv.w * wb.w;
  #pragma unroll
  for (int m = 1; m < 64; m <<= 1) s += __shfl_xor(s, m, 64);
  if (lane == 0) bvec[row] = s;
}

// ---------------- weight repack to B-fragment-linear bf16 ------------------
// wfrag[w][ks][nt][lane][i] = W[16*nt + (lane&15)][32*ks + 8*(lane>>4) + i]
__global__ __launch_bounds__(64) void k_wrep(const float* __restrict__ zw,
                                             const float* __restrict__ rw,
                                             const float* __restrict__ fw,
                                             u16* __restrict__ wfrag) {
  const int lane = threadIdx.x & 63;
  const int idx = blockIdx.x;                   // 0..767
  const int w = idx >> 8, rem = idx & 255, ks = rem >> 4, nt = rem & 15;
  const float* W = (w == 0) ? zw : ((w == 1) ? rw : fw);
  const int n = lane & 15, g = lane >> 4;
  const float* src = W + (size_t)(nt * 16 + n) * 512 + ks * 32 + g * 8;
  u16x8 o;
  #pragma unroll
  for (int i = 0; i < 8; ++i) o[i] = f2bf(src[i]);
  *reinterpret_cast<u16x8*>(wfrag + ((size_t)(w * 256 + ks * 16 + nt) * 64 + lane) * 8) = o;
}

// ---------------- flash attention (R2) -------------------------------------
// grid 256 = (itile, b) with b = blockIdx%8 (XCD swizzle). 512 threads =
// 8 waves: wave w -> row quarter wr=w&3 (16 rows), j-half wg=w>>2 (1024 j).
// Each wave: full 256-col O accumulator (64 VGPR), KVBLK=64 V^T staged
// cooperatively per group into swizzled LDS. 2-way flash merge at end.
__global__ __launch_bounds__(512, 1) void k_attn(const u16* __restrict__ qb,
                                                 const u16* __restrict__ xb,
                                                 const float* __restrict__ bvec,
                                                 u16* __restrict__ attnb) {
  extern __shared__ u16 lds[];
  // [0, 65536): vt[2 group][256 f][64 j] bf16, XOR-swizzled. Reused as Of f32[64][256] (swizzled).
  // [65536, 81920): pl[8 wave][16 row][64 j] bf16, XOR-swizzled.
  // [81920, 82432): ML f32[64 row][2]
  const int tid = threadIdx.x;
  const int w = tid >> 6, lane = tid & 63;
  const int wr = w & 3, wg = w >> 2;
  const int n = lane & 15, g = lane >> 4;
  const int b = blockIdx.x & 7, itile = blockIdx.x >> 3;
  const int i0 = itile * 64;
  const size_t xbase = (size_t)b * (NS * NF);

  char* vt = reinterpret_cast<char*>(lds) + wg * 32768;
  char* pl = reinterpret_cast<char*>(lds) + 65536 + w * 2048;
  float* ML = reinterpret_cast<float*>(reinterpret_cast<char*>(lds) + 81920);

  // Q fragments for this wave's 16 rows: 8 ks chunks
  u16x8 qf[8];
  {
    const u16* qrow = qb + xbase + (size_t)(i0 + 16 * wr + n) * NF + 8 * g;
    #pragma unroll
    for (int ks = 0; ks < 8; ++ks) qf[ks] = *reinterpret_cast<const u16x8*>(qrow + 32 * ks);
  }

  f32x4 O[16];
  #pragma unroll
  for (int nf = 0; nf < 16; ++nf) O[nf] = 0.f;
  float mrow[4], lrow[4];
  #pragma unroll
  for (int r = 0; r < 4; ++r) { mrow[r] = -__builtin_inff(); lrow[r] = 0.f; }

  for (int jtt = 0; jtt < 16; ++jtt) {
    const int j0 = wg * 1024 + jtt * 64;
    // ---- stage V^T tile [256 f][64 j] (group-cooperative, pair-packed) ----
    {
      const int tg = tid & 255;
      const int pr = tg >> 3, a = tg & 7;            // j-pair 0..31, f-chunk
      #pragma unroll
      for (int it = 0; it < 4; ++it) {
        const int c = 8 * (a + 8 * it);
        const u16* r0 = xb + xbase + (size_t)(j0 + 2 * pr) * NF + c;
        u16x8 v0 = *reinterpret_cast<const u16x8*>(r0);
        u16x8 v1 = *reinterpret_cast<const u16x8*>(r0 + NF);
        #pragma unroll
        for (int i = 0; i < 8; ++i) {
          const int f = c + i;
          const u32 pk = (u32)v0[i] | ((u32)v1[i] << 16);
          const int byte = (f * 128 + 4 * pr) ^ ((f & 7) << 4);
          *reinterpret_cast<u32*>(vt + byte) = pk;
        }
      }
    }
    __syncthreads();
    // ---- QK^T: 4 nf x 8 ks, K B-frags direct from global (L1/L2) ----------
    f32x4 sc[4];
    #pragma unroll
    for (int nf = 0; nf < 4; ++nf) {
      f32x4 acc = 0.f;
      const u16* krow = xb + xbase + (size_t)(j0 + 16 * nf + n) * NF + 8 * g;
      #pragma unroll
      for (int ks = 0; ks < 8; ++ks) {
        u16x8 kf = *reinterpret_cast<const u16x8*>(krow + 32 * ks);
        acc = MFMA16(qf[ks], kf, acc);
      }
      const float bv = bvec[b * NS + j0 + 16 * nf + n];
      #pragma unroll
      for (int r = 0; r < 4; ++r) sc[nf][r] = acc[r] + bv;
    }
    // ---- online softmax (rows = 4g+r, cols = n across 4 nf) ---------------
    float pmax[4];
    #pragma unroll
    for (int r = 0; r < 4; ++r) {
      float v = fmaxf(fmaxf(sc[0][r], sc[1][r]), fmaxf(sc[2][r], sc[3][r]));
      #pragma unroll
      for (int m = 1; m < 16; m <<= 1) v = fmaxf(v, __shfl_xor(v, m, 64));
      pmax[r] = v;
    }
    int needi = 0;
    #pragma unroll
    for (int r = 0; r < 4; ++r) needi |= (pmax[r] > mrow[r] + 8.0f) ? 1 : 0;
    if (__any(needi)) {               // T13 defer-max
      #pragma unroll
      for (int r = 0; r < 4; ++r) {
        const float mn = fmaxf(mrow[r], pmax[r]);
        const float scl = __expf(mrow[r] - mn);
        mrow[r] = mn; lrow[r] *= scl;
        #pragma unroll
        for (int nf = 0; nf < 16; ++nf) O[nf][r] *= scl;
      }
    }
    float p[4][4];
    #pragma unroll
    for (int nf = 0; nf < 4; ++nf)
      #pragma unroll
      for (int r = 0; r < 4; ++r) p[nf][r] = __expf(sc[nf][r] - mrow[r]);
    #pragma unroll
    for (int r = 0; r < 4; ++r) {
      float s = p[0][r] + p[1][r] + p[2][r] + p[3][r];
      #pragma unroll
      for (int m = 1; m < 16; m <<= 1) s += __shfl_xor(s, m, 64);
      lrow[r] += s;
    }
    // ---- P -> pl (swizzled [16 row][64 j]) -> A-frags ---------------------
    #pragma unroll
    for (int nf = 0; nf < 4; ++nf)
      #pragma unroll
      for (int r = 0; r < 4; ++r) {
        const int row = 4 * g + r, col = 16 * nf + n;
        const int byte = (row * 128 + 2 * col) ^ ((row & 7) << 4);
        *reinterpret_cast<u16*>(pl + byte) = f2bf(p[nf][r]);
      }
    // ---- PV: 2 ks2 x 16 nf ------------------------------------------------
    #pragma unroll
    for (int ks2 = 0; ks2 < 2; ++ks2) {
      const int pbyte = (n * 128 + 16 * g + 64 * ks2) ^ ((n & 7) << 4);
      u16x8 pa = *reinterpret_cast<const u16x8*>(pl + pbyte);
      #pragma unroll
      for (int nf16 = 0; nf16 < 16; ++nf16) {
        const int f = 16 * nf16 + n;
        const int vbyte = (f * 128 + 16 * g + 64 * ks2) ^ ((f & 7) << 4);
        u16x8 vf = *reinterpret_cast<const u16x8*>(vt + vbyte);
        O[nf16] = MFMA16(pa, vf, O[nf16]);
      }
    }
    __syncthreads();
  }

  // ---- 2-way flash merge across j-halves ----------------------------------
  float* Of = reinterpret_cast<float*>(lds);          // [64 row][256 f] swizzled
  if (wg == 1) {
    #pragma unroll
    for (int nf16 = 0; nf16 < 16; ++nf16)
      #pragma unroll
      for (int r = 0; r < 4; ++r) {
        const int row = 16 * wr + 4 * g + r, col = 16 * nf16 + n;
        const int byte = (row * 1024 + 4 * col) ^ ((((unsigned)row >> 2) & 3) << 4);
        *reinterpret_cast<float*>(reinterpret_cast<char*>(Of) + byte) = O[nf16][r];
      }
    if (n == 0) {
      #pragma unroll
      for (int r = 0; r < 4; ++r) {
        const int row = 16 * wr + 4 * g + r;
        ML[row * 2] = mrow[r]; ML[row * 2 + 1] = lrow[r];
      }
    }
  }
  __syncthreads();
  if (wg == 0) {
    float f0[4], f1[4], rL[4];
    #pragma unroll
    for (int r = 0; r < 4; ++r) {
      const int row = 16 * wr + 4 * g + r;
      const float m1 = ML[row * 2], l1 = ML[row * 2 + 1];
      const float M = fmaxf(mrow[r], m1);
      f0[r] = __expf(mrow[r] - M); f1[r] = __expf(m1 - M);
      rL[r] = 1.0f / (lrow[r] * f0[r] + l1 * f1[r]);
    }
    #pragma unroll
    for (int nf16 = 0; nf16 < 16; ++nf16)
      #pragma unroll
      for (int r = 0; r < 4; ++r) {
        const int row = 16 * wr + 4 * g + r, col = 16 * nf16 + n;
        const int byte = (row * 1024 + 4 * col) ^ ((((unsigned)row >> 2) & 3) << 4);
        const float o1 = *reinterpret_cast<const float*>(reinterpret_cast<char*>(Of) + byte);
        const float v = (O[nf16][r] * f0[r] + o1 * f1[r]) * rL[r];
        attnb[xbase + (size_t)(i0 + row) * NF + col] = f2bf(v);
      }
  }
}

// ---------------- fused gate GEMMs + epilogue ------------------------------
__global__ __launch_bounds__(256, 1) void k_gate(const u16* __restrict__ xb,
                                                 const u16* __restrict__ attnb,
                                                 const float* __restrict__ x,
                                                 const float* __restrict__ zb,
                                                 const float* __restrict__ rb,
                                                 const float* __restrict__ fb,
                                                 const u16* __restrict__ wfrag,
                                                 float* __restrict__ out) {
  const int tid = threadIdx.x, w = tid >> 6, lane = tid & 63;
  const int rg = w & 1, nh = w >> 1;
  const int m0 = blockIdx.x * 64 + rg * 32;
  const int n = lane & 15, g = lane >> 4;

  u16x8 af[2][16];
  #pragma unroll
  for (int mf = 0; mf < 2; ++mf) {
    const int row = m0 + 16 * mf + n;
    const u16* xr = xb + (size_t)row * NF + 8 * g;
    #pragma unroll
    for (int ks = 0; ks < 8; ++ks) af[mf][ks] = *reinterpret_cast<const u16x8*>(xr + 32 * ks);
    const u16* ar = attnb + (size_t)row * NF + 8 * g;
    #pragma unroll
    for (int ks = 0; ks < 8; ++ks) af[mf][8 + ks] = *reinterpret_cast<const u16x8*>(ar + 32 * ks);
  }
  for (int nt2 = 0; nt2 < 8; ++nt2) {
    const int nt = 8 * nh + nt2;
    const int col = 16 * nt + n;
    f32x4 za[2], ra[2], fa[2];
    {
      const float z0 = zb[col], r0 = rb[col], f0 = fb[col];
      #pragma unroll
      for (int mf = 0; mf < 2; ++mf) { za[mf] = z0; ra[mf] = r0; fa[mf] = f0; }
    }
    #pragma unroll
    for (int ks = 0; ks < 16; ++ks) {
      const size_t base = ((size_t)(ks * 16 + nt) * 64 + lane) * 8;
      u16x8 bz = *reinterpret_cast<const u16x8*>(wfrag + base);
      u16x8 br = *reinterpret_cast<const u16x8*>(wfrag + (size_t)256 * 64 * 8 + base);
      u16x8 bff = *reinterpret_cast<const u16x8*>(wfrag + (size_t)512 * 64 * 8 + base);
      #pragma unroll
      for (int mf = 0; mf < 2; ++mf) {
        za[mf] = MFMA16(af[mf][ks], bz, za[mf]);
        ra[mf] = MFMA16(af[mf][ks], br, ra[mf]);
        fa[mf] = MFMA16(af[mf][ks], bff, fa[mf]);
      }
    }
    #pragma unroll
    for (int mf = 0; mf < 2; ++mf)
      #pragma unroll
      for (int r = 0; r < 4; ++r) {
        const int row = m0 + 16 * mf + 4 * g + r;
        const float xv = x[(size_t)row * NF + col];
        const float zv = 2.f / (1.f + __expf(-2.f * za[mf][r])) - 1.f;  // tanh
        const float rv = 1.f / (1.f + __expf(-ra[mf][r]));
        const float fv = 1.f / (1.f + __expf(-fa[mf][r]));
        out[(size_t)row * NF + col] = rv * xv + fv * zv;
      }
  }
}

// ---------------------------------------------------------------------------
extern "C" void kernel_launch(void* const* d_in, const int* in_sizes, int n_in,
                              void* d_out, int out_size, void* d_ws, size_t ws_size,
                              hipStream_t stream) {
  const float* x    = (const float*)d_in[0];
  const float* attw = (const float*)d_in[1];
  const float* zw   = (const float*)d_in[2];
  const float* zb   = (const float*)d_in[3];
  const float* rw   = (const float*)d_in[4];
  const float* rb   = (const float*)d_in[5];
  const float* fw   = (const float*)d_in[6];
  const float* fb   = (const float*)d_in[7];
  float* out = (float*)d_out;

  char* ws = (char*)d_ws;
  u16*   qb    = (u16*)(ws);                       //  8 MB
  u16*   xbb   = (u16*)(ws + 8388608);             //  8 MB
  u16*   attnb = (u16*)(ws + 16777216);            //  8 MB
  float* bvec  = (float*)(ws + 25165824);          // 64 KB
  u16*   wfrag = (u16*)(ws + 25231360);            // 768 KB

  (void)hipFuncSetAttribute((const void*)k_attn,
      hipFuncAttributeMaxDynamicSharedMemorySize, 82432);

  k_prep<<<NR / 4, 256, 0, stream>>>(x, attw, qb, xbb, bvec);
  k_wrep<<<768, 64, 0, stream>>>(zw, rw, fw, wfrag);
  k_attn<<<256, 512, 82432, stream>>>(qb, xbb, bvec, attnb);
  k_gate<<<256, 256, 0, stream>>>(xbb, attnb, x, zb, rb, fb, wfrag, out);
}